// Round 1
// baseline (416.368 us; speedup 1.0000x reference)
//
#include <hip/hip_runtime.h>

#define M_FFT   4096      // half-length complex FFT size (real n = 8192)
#define HALF_M  2048
#define THREADS 256
#define B_DIM   4
#define H_DIM   1024
#define L_DIM   4096

#define PI_F 3.14159265358979323846f

__device__ __forceinline__ float2 cmul(float2 a, float2 b) {
    return make_float2(a.x * b.x - a.y * b.y, a.x * b.y + a.y * b.x);
}

// In-place radix-2 DIT FFT over 4096 complex elements in LDS.
// Input must be in bit-reversed order; output natural order.
// sgn = -1 forward (e^{-2pi i}), +1 inverse (unscaled).
__device__ __forceinline__ void fft_lds(float2* Z, int tid, float sgn) {
    const float base = sgn * (PI_F / (float)HALF_M); // angle per twiddle-table index
    for (int half = 1; half <= HALF_M; half <<= 1) {
        int tstride = HALF_M / half;
        __syncthreads();
        for (int bb = tid; bb < HALF_M; bb += THREADS) {
            int pos = bb & (half - 1);
            int i0  = (bb << 1) - pos;   // grp*2*half + pos
            int i1  = i0 + half;
            float ang = base * (float)(pos * tstride);
            float sn, cs;
            __sincosf(ang, &sn, &cs);
            float2 a = Z[i0], c = Z[i1];
            float tr = c.x * cs - c.y * sn;
            float ti = c.x * sn + c.y * cs;
            Z[i0] = make_float2(a.x + tr, a.y + ti);
            Z[i1] = make_float2(a.x - tr, a.y - ti);
        }
    }
    __syncthreads();
}

__device__ __forceinline__ int bitrev12(int n) {
    return (int)(__brev((unsigned)n) >> 20);
}

__global__ __launch_bounds__(THREADS, 2)
void fftconv_kernel(const float* __restrict__ x, const float* __restrict__ k,
                    float* __restrict__ out) {
    __shared__ float2 Zx[M_FFT];
    __shared__ float2 Zk[M_FFT];

    const int tid = threadIdx.x;
    const int wg  = blockIdx.x;
    const int h   = wg & (H_DIM - 1);
    const int b   = wg >> 10;

    const float2* xp = (const float2*)(x + ((size_t)(b * H_DIM + h)) * L_DIM);
    const float2* kp = (const float2*)(k + (size_t)h * L_DIM);

    // Load & pack: z[n] = a[2n] + i a[2n+1]; real input is zero-padded to 8192,
    // so z[n] = 0 for n >= 2048. Store at bit-reversed position for DIT.
    for (int n = tid; n < HALF_M; n += THREADS) {
        int r = bitrev12(n);
        Zx[r] = xp[n];
        Zk[r] = kp[n];
    }
    for (int n = HALF_M + tid; n < M_FFT; n += THREADS) {
        int r = bitrev12(n);
        Zx[r] = make_float2(0.f, 0.f);
        Zk[r] = make_float2(0.f, 0.f);
    }

    fft_lds(Zx, tid, -1.0f);   // forward FFT of packed x
    fft_lds(Zk, tid, -1.0f);   // forward FFT of packed k

    // Combine: unpack rfft bins A[k] from Z, multiply spectra, repack into Z'
    // for the inverse half-length FFT. All reads before the barrier, results
    // held in registers, then scattered (bit-reversed) back into Zx.
    float2 rA[8], rB[8];
    #pragma unroll
    for (int s = 0; s < 8; ++s) {
        int j = tid + THREADS * s;
        if (j == 0) {
            // bins 0 and M (both real):
            float2 zx = Zx[0], zk = Zk[0];
            float ax0 = zx.x + zx.y, axM = zx.x - zx.y;
            float ak0 = zk.x + zk.y, akM = zk.x - zk.y;
            float y0 = ax0 * ak0, yM = axM * akM;
            // Z'[0] = 0.5(y0+yM) + i 0.5(y0-yM)
            rA[s] = make_float2(0.5f * (y0 + yM), 0.5f * (y0 - yM));
            // self-paired j = 2048: A = conj(Z[2048]); Z'[2048] = Zx[2048]*Zk[2048]
            float2 zx2 = Zx[HALF_M], zk2 = Zk[HALF_M];
            rB[s] = cmul(zx2, zk2);
        } else {
            int jm = M_FFT - j;
            float2 zxj = Zx[j], zxm = Zx[jm];
            float2 zkj = Zk[j], zkm = Zk[jm];
            float ang = -PI_F * (float)j / (float)M_FFT;  // W_N^j, N = 8192
            float sn, cs;
            __sincosf(ang, &sn, &cs);
            float2 w = make_float2(cs, sn);

            // x spectrum bins: Xe = (Zj + conj(Zm))/2, Xo = -i(Zj - conj(Zm))/2
            float2 Xe = make_float2(0.5f * (zxj.x + zxm.x), 0.5f * (zxj.y - zxm.y));
            float2 dx = make_float2(zxj.x - zxm.x, zxj.y + zxm.y);
            float2 Xo = make_float2(0.5f * dx.y, -0.5f * dx.x);
            float2 tx = cmul(w, Xo);
            float2 Axj = make_float2(Xe.x + tx.x, Xe.y + tx.y);
            float2 Axm = make_float2(Xe.x - tx.x, -(Xe.y - tx.y)); // conj(Xe - t)

            // k spectrum bins:
            float2 Ke = make_float2(0.5f * (zkj.x + zkm.x), 0.5f * (zkj.y - zkm.y));
            float2 dk = make_float2(zkj.x - zkm.x, zkj.y + zkm.y);
            float2 Ko = make_float2(0.5f * dk.y, -0.5f * dk.x);
            float2 tk = cmul(w, Ko);
            float2 Akj = make_float2(Ke.x + tk.x, Ke.y + tk.y);
            float2 Akm = make_float2(Ke.x - tk.x, -(Ke.y - tk.y));

            float2 Yj = cmul(Axj, Akj);
            float2 Ym = cmul(Axm, Akm);

            // inverse repack: u = (Yj + conj(Ym))/2 ; v = conj(w)*(Yj - conj(Ym))/2
            float2 u  = make_float2(0.5f * (Yj.x + Ym.x), 0.5f * (Yj.y - Ym.y));
            float2 dd = make_float2(Yj.x - Ym.x, Yj.y + Ym.y);
            float2 wc = make_float2(w.x, -w.y);
            float2 v  = cmul(wc, dd);
            v.x *= 0.5f; v.y *= 0.5f;
            // Z'[j] = u + i v ; Z'[jm] = conj(u - i v)
            rA[s] = make_float2(u.x - v.y, u.y + v.x);
            rB[s] = make_float2(u.x + v.y, -(u.y - v.x));
        }
    }
    __syncthreads();
    #pragma unroll
    for (int s = 0; s < 8; ++s) {
        int j = tid + THREADS * s;
        int i0, i1;
        if (j == 0) { i0 = 0; i1 = 1; }              // bitrev(0), bitrev(2048)
        else        { i0 = bitrev12(j); i1 = bitrev12(M_FFT - j); }
        Zx[i0] = rA[s];
        Zx[i1] = rB[s];
    }

    fft_lds(Zx, tid, 1.0f);    // inverse FFT (unscaled)

    // Write first 4096 real outputs: y[2n] = Re z'[n], y[2n+1] = Im z'[n], /M
    float2* op = (float2*)(out + ((size_t)(b * H_DIM + h)) * L_DIM);
    const float scale = 1.0f / (float)M_FFT;
    for (int n = tid; n < HALF_M; n += THREADS) {
        float2 z = Zx[n];
        op[n] = make_float2(z.x * scale, z.y * scale);
    }
}

extern "C" void kernel_launch(void* const* d_in, const int* in_sizes, int n_in,
                              void* d_out, int out_size, void* d_ws, size_t ws_size,
                              hipStream_t stream) {
    const float* x = (const float*)d_in[0];
    const float* k = (const float*)d_in[1];
    float* out = (float*)d_out;
    fftconv_kernel<<<dim3(B_DIM * H_DIM), dim3(THREADS), 0, stream>>>(x, k, out);
}

// Round 2
// 193.431 us; speedup vs baseline: 2.1525x; 2.1525x over previous
//
#include <hip/hip_runtime.h>

#define THREADS 256
#define B_DIM   4
#define H_DIM   1024
#define L_DIM   4096
#define NFFT    4096      // half-length complex FFT size (real n = 8192)
#define PI_F     3.14159265358979323846f
#define TWO_PI_F 6.28318530717958647692f

__device__ __forceinline__ float2 cmulf(float2 a, float2 b) {
    return make_float2(a.x*b.x - a.y*b.y, a.x*b.y + a.y*b.x);
}
__device__ __forceinline__ float2 caddf(float2 a, float2 b){ return make_float2(a.x+b.x, a.y+b.y); }
__device__ __forceinline__ float2 csubf(float2 a, float2 b){ return make_float2(a.x-b.x, a.y-b.y); }

// XOR swizzle: bank-pair = d2^d1^d0 -> ~4 lanes/bank-pair (b64 floor) on all patterns
__device__ __forceinline__ int swz(int i) { return i ^ ((i>>4)&15) ^ ((i>>8)&15); }

// W16^q = e^{SGN*2pi*i*q/16}
__device__ __forceinline__ float2 w16c(int q, float s) {
    constexpr float C[8] = {1.f, 0.9238795325f, 0.7071067812f, 0.3826834324f,
                            0.f, -0.3826834324f, -0.7071067812f, -0.9238795325f};
    constexpr float S[8] = {0.f, 0.3826834324f, 0.7071067812f, 0.9238795325f,
                            1.f, 0.9238795325f, 0.7071067812f, 0.3826834324f};
    return make_float2(C[q], s*S[q]);
}

template<int SGN>
__device__ __forceinline__ float2 twq(float2 d, int q) {
    if (q == 0) return d;
    if (q == 4) return make_float2((float)(-SGN)*d.y, (float)SGN*d.x);
    return cmulf(d, w16c(q, (float)SGN));
}

// Radix-2 DIF 16-pt DFT: natural-order input, bit-reversed output (bin k at reg REV4[k]).
// HZ: inputs 8..15 are implicit zeros (not read).
template<int SGN, bool HZ>
__device__ __forceinline__ void dif16(float2 v[16]) {
    if (HZ) {
        #pragma unroll
        for (int i = 0; i < 8; ++i) {
            float2 a = v[i];
            v[i+8] = twq<SGN>(a, i);        // (a - 0) * W16^i ; v[i] = a + 0
        }
    } else {
        #pragma unroll
        for (int i = 0; i < 8; ++i) {
            float2 a = v[i], b = v[i+8];
            v[i]   = caddf(a,b);
            v[i+8] = twq<SGN>(csubf(a,b), i);
        }
    }
    #pragma unroll
    for (int h = 4; h >= 1; h >>= 1) {
        const int step = 8 / h;
        #pragma unroll
        for (int g = 0; g < 16; g += 2*h) {
            #pragma unroll
            for (int i = 0; i < h; ++i) {
                float2 a = v[g+i], b = v[g+i+h];
                v[g+i]   = caddf(a,b);
                v[g+i+h] = twq<SGN>(csubf(a,b), i*step);
            }
        }
    }
}

// Radix-2 DIT 16-pt DFT: bit-reversed input (bin k at reg REV4[k]), natural-order output.
template<int SGN>
__device__ __forceinline__ void dit16(float2 v[16]) {
    #pragma unroll
    for (int h = 1; h <= 8; h <<= 1) {
        const int step = 8 / h;
        #pragma unroll
        for (int g = 0; g < 16; g += 2*h) {
            #pragma unroll
            for (int i = 0; i < h; ++i) {
                float2 a = v[g+i];
                float2 b = twq<SGN>(v[g+i+h], i*step);
                v[g+i]   = caddf(a,b);
                v[g+i+h] = csubf(a,b);
            }
        }
    }
}

__global__ __launch_bounds__(THREADS, 2)
void fftconv_kernel(const float* __restrict__ x, const float* __restrict__ k,
                    float* __restrict__ out) {
    __shared__ float2 Zx[NFFT];
    __shared__ float2 Zk[NFFT];
    constexpr int REV4[16] = {0,8,4,12,2,10,6,14,1,9,5,13,3,11,7,15};

    const int t  = threadIdx.x;
    const int wg = blockIdx.x;
    const int hh = wg & (H_DIM - 1);
    const int b  = wg >> 10;

    const float2* xp = (const float2*)(x + ((size_t)(b*H_DIM + hh)) * L_DIM);
    const float2* kp = (const float2*)(k + (size_t)hh * L_DIM);

    float2 vx[16], vk[16];

    // ---- forward level 1: z[n1*256 + t], n1 = 0..15 (upper half zero) ----
    #pragma unroll
    for (int r = 0; r < 8; ++r) {
        vx[r] = xp[256*r + t];
        vk[r] = kp[256*r + t];
    }
    dif16<-1, true>(vx);
    dif16<-1, true>(vk);
    {
        const float base = -TWO_PI_F * (float)t / (float)NFFT;
        #pragma unroll
        for (int kk = 1; kk < 16; ++kk) {
            float sn, cs; __sincosf(base * (float)kk, &sn, &cs);
            float2 w = make_float2(cs, sn);
            vx[REV4[kk]] = cmulf(vx[REV4[kk]], w);
            vk[REV4[kk]] = cmulf(vk[REV4[kk]], w);
        }
    }
    #pragma unroll
    for (int kk = 0; kk < 16; ++kk) {
        int p = swz(256*kk + t);
        Zx[p] = vx[REV4[kk]];
        Zk[p] = vk[REV4[kk]];
    }
    __syncthreads();

    // ---- forward level 2: within row k1 (256 long), stride-16 over r, low digit m ----
    const int k1 = t >> 4, m = t & 15;
    const int rb = 256*k1 + m;
    #pragma unroll
    for (int r = 0; r < 16; ++r) {
        int p = swz(rb + 16*r);
        vx[r] = Zx[p]; vk[r] = Zk[p];
    }
    dif16<-1,false>(vx);
    dif16<-1,false>(vk);
    {
        const float base = -TWO_PI_F * (float)m / 256.f;
        #pragma unroll
        for (int kk = 1; kk < 16; ++kk) {
            float sn, cs; __sincosf(base * (float)kk, &sn, &cs);
            float2 w = make_float2(cs, sn);
            vx[REV4[kk]] = cmulf(vx[REV4[kk]], w);
            vk[REV4[kk]] = cmulf(vk[REV4[kk]], w);
        }
    }
    #pragma unroll
    for (int kk = 0; kk < 16; ++kk) {
        int p = swz(rb + 16*kk);
        Zx[p] = vx[REV4[kk]]; Zk[p] = vk[REV4[kk]];
    }
    __syncthreads();

    // ---- forward level 3: contiguous 16-blocks, no twiddle ----
    const int b3 = t << 4;
    #pragma unroll
    for (int r = 0; r < 16; ++r) {
        int p = swz(b3 + r);
        vx[r] = Zx[p]; vk[r] = Zk[p];
    }
    dif16<-1,false>(vx);
    dif16<-1,false>(vk);
    #pragma unroll
    for (int kk = 0; kk < 16; ++kk) {
        int p = swz(b3 + kk);
        Zx[p] = vx[REV4[kk]]; Zk[p] = vk[REV4[kk]];
    }
    __syncthreads();
    // Storage now: position p holds bin drev(p) (base-16 digit reversal).

    // ---- combine: unpack half-complex spectra, multiply, repack (in-place on Zx) ----
    #pragma unroll
    for (int s = 0; s < 8; ++s) {
        int j = t + 256*s;
        if (j == 0) {
            // bins 0 and M (both real); self-paired bin 2048 at position drev(2048)=8
            float2 zx = Zx[0], zk = Zk[0];
            float ax0 = zx.x + zx.y, axM = zx.x - zx.y;
            float ak0 = zk.x + zk.y, akM = zk.x - zk.y;
            float y0 = ax0*ak0, yM = axM*akM;
            Zx[0] = make_float2(0.5f*(y0+yM), 0.5f*(y0-yM));
            int p2 = swz(8);
            float2 zx2 = Zx[p2], zk2 = Zk[p2];
            Zx[p2] = cmulf(zx2, zk2);
        } else {
            int jm = NFFT - j;
            int pj = swz( ((j&15)<<8)  | (((j>>4)&15)<<4)  | (j>>8)  );
            int pm = swz( ((jm&15)<<8) | (((jm>>4)&15)<<4) | (jm>>8) );
            float2 zxj = Zx[pj], zxm = Zx[pm];
            float2 zkj = Zk[pj], zkm = Zk[pm];

            float ang = -PI_F * (float)j / (float)NFFT;   // W_8192^j
            float sn, cs; __sincosf(ang, &sn, &cs);
            float2 w = make_float2(cs, sn);

            float2 Xe = make_float2(0.5f*(zxj.x + zxm.x), 0.5f*(zxj.y - zxm.y));
            float2 dx = make_float2(zxj.x - zxm.x, zxj.y + zxm.y);
            float2 Xo = make_float2(0.5f*dx.y, -0.5f*dx.x);
            float2 tx = cmulf(w, Xo);
            float2 Axj = caddf(Xe, tx);
            float2 Axm = make_float2(Xe.x - tx.x, -(Xe.y - tx.y));

            float2 Ke = make_float2(0.5f*(zkj.x + zkm.x), 0.5f*(zkj.y - zkm.y));
            float2 dk = make_float2(zkj.x - zkm.x, zkj.y + zkm.y);
            float2 Ko = make_float2(0.5f*dk.y, -0.5f*dk.x);
            float2 tk = cmulf(w, Ko);
            float2 Akj = caddf(Ke, tk);
            float2 Akm = make_float2(Ke.x - tk.x, -(Ke.y - tk.y));

            float2 Yj = cmulf(Axj, Akj);
            float2 Ym = cmulf(Axm, Akm);

            float2 u  = make_float2(0.5f*(Yj.x + Ym.x), 0.5f*(Yj.y - Ym.y));
            float2 dd = make_float2(Yj.x - Ym.x, Yj.y + Ym.y);
            float2 wc = make_float2(w.x, -w.y);
            float2 vv = cmulf(wc, dd);
            vv.x *= 0.5f; vv.y *= 0.5f;
            Zx[pj] = make_float2(u.x - vv.y, u.y + vv.x);
            Zx[pm] = make_float2(u.x + vv.y, -(u.y - vv.x));
        }
    }
    __syncthreads();

    // ---- inverse level A (T3^-1): contiguous 16-blocks, pure iDFT ----
    #pragma unroll
    for (int r = 0; r < 16; ++r) vx[REV4[r]] = Zx[swz(b3 + r)];
    dit16<1>(vx);
    #pragma unroll
    for (int mm = 0; mm < 16; ++mm) Zx[swz(b3 + mm)] = vx[mm];
    __syncthreads();

    // ---- inverse level B (T2^-1): untwiddle then iDFT over stride-16 ----
    {
        const float base = TWO_PI_F * (float)m / 256.f;
        #pragma unroll
        for (int kk = 0; kk < 16; ++kk) {
            float2 val = Zx[swz(rb + 16*kk)];
            if (kk > 0) {
                float sn, cs; __sincosf(base * (float)kk, &sn, &cs);
                val = cmulf(val, make_float2(cs, sn));
            }
            vx[REV4[kk]] = val;
        }
        dit16<1>(vx);
        #pragma unroll
        for (int r = 0; r < 16; ++r) Zx[swz(rb + 16*r)] = vx[r];
    }
    __syncthreads();

    // ---- inverse level C (T1^-1): untwiddle, iDFT over stride-256, store to global ----
    {
        const float base = TWO_PI_F * (float)t / (float)NFFT;
        #pragma unroll
        for (int kk = 0; kk < 16; ++kk) {
            float2 val = Zx[swz(256*kk + t)];
            if (kk > 0) {
                float sn, cs; __sincosf(base * (float)kk, &sn, &cs);
                val = cmulf(val, make_float2(cs, sn));
            }
            vx[REV4[kk]] = val;
        }
        dit16<1>(vx);
        float2* op = (float2*)(out + ((size_t)(b*H_DIM + hh)) * L_DIM);
        const float sc = 1.f / (float)NFFT;
        #pragma unroll
        for (int n1 = 0; n1 < 8; ++n1) {   // only first 4096 real outputs
            float2 z = vx[n1];
            op[256*n1 + t] = make_float2(z.x*sc, z.y*sc);
        }
    }
}

extern "C" void kernel_launch(void* const* d_in, const int* in_sizes, int n_in,
                              void* d_out, int out_size, void* d_ws, size_t ws_size,
                              hipStream_t stream) {
    const float* x = (const float*)d_in[0];
    const float* k = (const float*)d_in[1];
    float* out = (float*)d_out;
    fftconv_kernel<<<dim3(B_DIM * H_DIM), dim3(THREADS), 0, stream>>>(x, k, out);
}

// Round 3
// 176.368 us; speedup vs baseline: 2.3608x; 1.0967x over previous
//
#include <hip/hip_runtime.h>

#define THREADS 256
#define B_DIM   4
#define H_DIM   1024
#define L_DIM   4096
#define NFFT    4096      // half-length complex FFT size (real n = 8192)
#define PI_F     3.14159265358979323846f
#define TWO_PI_F 6.28318530717958647692f

__device__ __forceinline__ float2 cmulf(float2 a, float2 b) {
    return make_float2(a.x*b.x - a.y*b.y, a.x*b.y + a.y*b.x);
}
__device__ __forceinline__ float2 caddf(float2 a, float2 b){ return make_float2(a.x+b.x, a.y+b.y); }
__device__ __forceinline__ float2 csubf(float2 a, float2 b){ return make_float2(a.x-b.x, a.y-b.y); }

// XOR swizzle: bank-pair = d2^d1^d0 -> ~4 lanes/bank-pair (b64 floor) on all patterns
__device__ __forceinline__ int swz(int i) { return i ^ ((i>>4)&15) ^ ((i>>8)&15); }

// w[kk] = e^{i*base*kk}, kk=1..15, via 1 sincos + squaring tree (14 cmul)
__device__ __forceinline__ void make_tw(float base, float2 w[16]) {
    float sn, cs; __sincosf(base, &sn, &cs);
    w[1]  = make_float2(cs, sn);
    w[2]  = cmulf(w[1], w[1]);
    w[3]  = cmulf(w[2], w[1]);
    w[4]  = cmulf(w[2], w[2]);
    w[5]  = cmulf(w[4], w[1]);
    w[6]  = cmulf(w[4], w[2]);
    w[7]  = cmulf(w[4], w[3]);
    w[8]  = cmulf(w[4], w[4]);
    w[9]  = cmulf(w[8], w[1]);
    w[10] = cmulf(w[8], w[2]);
    w[11] = cmulf(w[8], w[3]);
    w[12] = cmulf(w[8], w[4]);
    w[13] = cmulf(w[8], w[5]);
    w[14] = cmulf(w[8], w[6]);
    w[15] = cmulf(w[8], w[7]);
}

// W16^q = e^{SGN*2pi*i*q/16}
__device__ __forceinline__ float2 w16c(int q, float s) {
    constexpr float C[8] = {1.f, 0.9238795325f, 0.7071067812f, 0.3826834324f,
                            0.f, -0.3826834324f, -0.7071067812f, -0.9238795325f};
    constexpr float S[8] = {0.f, 0.3826834324f, 0.7071067812f, 0.9238795325f,
                            1.f, 0.9238795325f, 0.7071067812f, 0.3826834324f};
    return make_float2(C[q], s*S[q]);
}

template<int SGN>
__device__ __forceinline__ float2 twq(float2 d, int q) {
    if (q == 0) return d;
    if (q == 4) return make_float2((float)(-SGN)*d.y, (float)SGN*d.x);
    return cmulf(d, w16c(q, (float)SGN));
}

// Radix-2 DIF 16-pt DFT: natural-order input, bit-reversed output (bin k at reg REV4[k]).
template<int SGN, bool HZ>
__device__ __forceinline__ void dif16(float2 v[16]) {
    if (HZ) {
        #pragma unroll
        for (int i = 0; i < 8; ++i) {
            float2 a = v[i];
            v[i+8] = twq<SGN>(a, i);
        }
    } else {
        #pragma unroll
        for (int i = 0; i < 8; ++i) {
            float2 a = v[i], b = v[i+8];
            v[i]   = caddf(a,b);
            v[i+8] = twq<SGN>(csubf(a,b), i);
        }
    }
    #pragma unroll
    for (int h = 4; h >= 1; h >>= 1) {
        const int step = 8 / h;
        #pragma unroll
        for (int g = 0; g < 16; g += 2*h) {
            #pragma unroll
            for (int i = 0; i < h; ++i) {
                float2 a = v[g+i], b = v[g+i+h];
                v[g+i]   = caddf(a,b);
                v[g+i+h] = twq<SGN>(csubf(a,b), i*step);
            }
        }
    }
}

// Radix-2 DIT 16-pt DFT: bit-reversed input, natural-order output.
template<int SGN>
__device__ __forceinline__ void dit16(float2 v[16]) {
    #pragma unroll
    for (int h = 1; h <= 8; h <<= 1) {
        const int step = 8 / h;
        #pragma unroll
        for (int g = 0; g < 16; g += 2*h) {
            #pragma unroll
            for (int i = 0; i < h; ++i) {
                float2 a = v[g+i];
                float2 b = twq<SGN>(v[g+i+h], i*step);
                v[g+i]   = caddf(a,b);
                v[g+i+h] = csubf(a,b);
            }
        }
    }
}

__device__ __constant__ int REV4_C[16] = {0,8,4,12,2,10,6,14,1,9,5,13,3,11,7,15};

// Forward 3-level radix-16 FFT of a zero-padded packed real row into LDS Z.
// On exit: position p holds bin drev(p) (base-16 digit reversal), swizzled.
__device__ __forceinline__ void fwd_fft_row(const float2* __restrict__ src, float2* Z, int t) {
    constexpr int REV4[16] = {0,8,4,12,2,10,6,14,1,9,5,13,3,11,7,15};
    float2 v[16], w[16];
    #pragma unroll
    for (int r = 0; r < 8; ++r) v[r] = src[256*r + t];
    dif16<-1, true>(v);
    make_tw(-TWO_PI_F * (float)t / (float)NFFT, w);
    #pragma unroll
    for (int kk = 1; kk < 16; ++kk) v[REV4[kk]] = cmulf(v[REV4[kk]], w[kk]);
    #pragma unroll
    for (int kk = 0; kk < 16; ++kk) Z[swz(256*kk + t)] = v[REV4[kk]];
    __syncthreads();

    const int k1 = t >> 4, m = t & 15;
    const int rb = 256*k1 + m;
    #pragma unroll
    for (int r = 0; r < 16; ++r) v[r] = Z[swz(rb + 16*r)];
    dif16<-1,false>(v);
    make_tw(-TWO_PI_F * (float)m / 256.f, w);
    #pragma unroll
    for (int kk = 1; kk < 16; ++kk) v[REV4[kk]] = cmulf(v[REV4[kk]], w[kk]);
    #pragma unroll
    for (int kk = 0; kk < 16; ++kk) Z[swz(rb + 16*kk)] = v[REV4[kk]];
    __syncthreads();

    const int b3 = t << 4;
    #pragma unroll
    for (int r = 0; r < 16; ++r) v[r] = Z[swz(b3 + r)];
    dif16<-1,false>(v);
    #pragma unroll
    for (int kk = 0; kk < 16; ++kk) Z[swz(b3 + kk)] = v[REV4[kk]];
}

// digit-reversed (base-16) position of bin j, swizzled
__device__ __forceinline__ int binpos(int j) {
    return swz( ((j&15)<<8) | (((j>>4)&15)<<4) | (j>>8) );
}

// ---------------- Kernel A: per-h rfft(k) spectrum -> ws (natural order) ----------------
__global__ __launch_bounds__(THREADS, 4)
void kfft_kernel(const float* __restrict__ k, float2* __restrict__ Kf_all) {
    __shared__ float2 Zk[NFFT];
    const int t  = threadIdx.x;
    const int hh = blockIdx.x;
    const float2* kp = (const float2*)(k + (size_t)hh * L_DIM);

    fwd_fft_row(kp, Zk, t);
    __syncthreads();

    float2* Kf = Kf_all + (size_t)hh * NFFT;
    #pragma unroll
    for (int s = 0; s < 8; ++s) {
        int j = t + 256*s;
        if (j == 0) {
            float2 zk = Zk[0];
            Kf[0] = make_float2(zk.x + zk.y, zk.x - zk.y);   // (A[0], A[M]) both real
            float2 zk2 = Zk[swz(8)];                          // Z[2048], drev(2048)=8
            Kf[2048] = make_float2(zk2.x, -zk2.y);            // A[2048] = conj(Z[2048])
        } else {
            int jm = NFFT - j;
            float2 zkj = Zk[binpos(j)], zkm = Zk[binpos(jm)];
            float sn, cs; __sincosf(-PI_F * (float)j / (float)NFFT, &sn, &cs);
            float2 w = make_float2(cs, sn);
            float2 Ke = make_float2(0.5f*(zkj.x + zkm.x), 0.5f*(zkj.y - zkm.y));
            float2 dk = make_float2(zkj.x - zkm.x, zkj.y + zkm.y);
            float2 Ko = make_float2(0.5f*dk.y, -0.5f*dk.x);
            float2 tk = cmulf(w, Ko);
            Kf[j]  = caddf(Ke, tk);
            Kf[jm] = make_float2(Ke.x - tk.x, -(Ke.y - tk.y));
        }
    }
}

// ---------------- Main kernel: x fwd FFT -> combine w/ global Kf -> inverse ----------------
__global__ __launch_bounds__(THREADS, 4)
void conv_main_kernel(const float* __restrict__ x, const float2* __restrict__ Kf_all,
                      float* __restrict__ out) {
    __shared__ float2 Zx[NFFT];
    constexpr int REV4[16] = {0,8,4,12,2,10,6,14,1,9,5,13,3,11,7,15};

    const int t  = threadIdx.x;
    const int wg = blockIdx.x;
    const int hh = wg & (H_DIM - 1);
    const int b  = wg >> 10;

    const float2* xp = (const float2*)(x + ((size_t)(b*H_DIM + hh)) * L_DIM);
    const float2* Kf = Kf_all + (size_t)hh * NFFT;

    fwd_fft_row(xp, Zx, t);

    // prefetch K spectrum while the barrier drains
    float2 kfj[8], kfm[8], kf2;
    #pragma unroll
    for (int s = 0; s < 8; ++s) {
        int j = t + 256*s;
        kfj[s] = Kf[j];
        kfm[s] = Kf[(NFFT - j) & (NFFT - 1)];
    }
    kf2 = Kf[2048];
    __syncthreads();

    // combine: unpack x half-complex bins, multiply by Kf, repack in place
    #pragma unroll
    for (int s = 0; s < 8; ++s) {
        int j = t + 256*s;
        if (j == 0) {
            float2 zx = Zx[0];
            float ax0 = zx.x + zx.y, axM = zx.x - zx.y;
            float y0 = ax0 * kfj[0].x, yM = axM * kfj[0].y;
            Zx[0] = make_float2(0.5f*(y0 + yM), 0.5f*(y0 - yM));
            int p2 = swz(8);
            float2 zx2 = Zx[p2];
            Zx[p2] = cmulf(zx2, make_float2(kf2.x, -kf2.y));  // Zx*conj(A_k)=Zx*Zk
        } else {
            int jm = NFFT - j;
            int pj = binpos(j), pm = binpos(jm);
            float2 zxj = Zx[pj], zxm = Zx[pm];

            float sn, cs; __sincosf(-PI_F * (float)j / (float)NFFT, &sn, &cs);
            float2 w = make_float2(cs, sn);

            float2 Xe = make_float2(0.5f*(zxj.x + zxm.x), 0.5f*(zxj.y - zxm.y));
            float2 dx = make_float2(zxj.x - zxm.x, zxj.y + zxm.y);
            float2 Xo = make_float2(0.5f*dx.y, -0.5f*dx.x);
            float2 tx = cmulf(w, Xo);
            float2 Axj = caddf(Xe, tx);
            float2 Axm = make_float2(Xe.x - tx.x, -(Xe.y - tx.y));

            float2 Yj = cmulf(Axj, kfj[s]);
            float2 Ym = cmulf(Axm, kfm[s]);

            float2 u  = make_float2(0.5f*(Yj.x + Ym.x), 0.5f*(Yj.y - Ym.y));
            float2 dd = make_float2(Yj.x - Ym.x, Yj.y + Ym.y);
            float2 wc = make_float2(w.x, -w.y);
            float2 vv = cmulf(wc, dd);
            vv.x *= 0.5f; vv.y *= 0.5f;
            Zx[pj] = make_float2(u.x - vv.y, u.y + vv.x);
            Zx[pm] = make_float2(u.x + vv.y, -(u.y - vv.x));
        }
    }
    __syncthreads();

    float2 vx[16], w[16];
    const int k1 = t >> 4, m = t & 15;
    const int rb = 256*k1 + m;
    const int b3 = t << 4;

    // inverse level A: contiguous 16-blocks, pure iDFT
    #pragma unroll
    for (int r = 0; r < 16; ++r) vx[REV4[r]] = Zx[swz(b3 + r)];
    dit16<1>(vx);
    #pragma unroll
    for (int mm = 0; mm < 16; ++mm) Zx[swz(b3 + mm)] = vx[mm];
    __syncthreads();

    // inverse level B: untwiddle then iDFT over stride-16
    make_tw(TWO_PI_F * (float)m / 256.f, w);
    #pragma unroll
    for (int kk = 0; kk < 16; ++kk) {
        float2 val = Zx[swz(rb + 16*kk)];
        if (kk > 0) val = cmulf(val, w[kk]);
        vx[REV4[kk]] = val;
    }
    dit16<1>(vx);
    #pragma unroll
    for (int r = 0; r < 16; ++r) Zx[swz(rb + 16*r)] = vx[r];
    __syncthreads();

    // inverse level C: untwiddle, iDFT over stride-256, store first 4096 reals
    make_tw(TWO_PI_F * (float)t / (float)NFFT, w);
    #pragma unroll
    for (int kk = 0; kk < 16; ++kk) {
        float2 val = Zx[swz(256*kk + t)];
        if (kk > 0) val = cmulf(val, w[kk]);
        vx[REV4[kk]] = val;
    }
    dit16<1>(vx);
    float2* op = (float2*)(out + ((size_t)(b*H_DIM + hh)) * L_DIM);
    const float sc = 1.f / (float)NFFT;
    #pragma unroll
    for (int n1 = 0; n1 < 8; ++n1) {
        float2 z = vx[n1];
        op[256*n1 + t] = make_float2(z.x*sc, z.y*sc);
    }
}

// ---------------- Fallback (R2, known-good): used if ws too small ----------------
__global__ __launch_bounds__(THREADS, 2)
void fftconv_fallback(const float* __restrict__ x, const float* __restrict__ k,
                      float* __restrict__ out) {
    __shared__ float2 Zx[NFFT];
    __shared__ float2 Zk[NFFT];
    constexpr int REV4[16] = {0,8,4,12,2,10,6,14,1,9,5,13,3,11,7,15};

    const int t  = threadIdx.x;
    const int wg = blockIdx.x;
    const int hh = wg & (H_DIM - 1);
    const int b  = wg >> 10;

    const float2* xp = (const float2*)(x + ((size_t)(b*H_DIM + hh)) * L_DIM);
    const float2* kp = (const float2*)(k + (size_t)hh * L_DIM);

    fwd_fft_row(xp, Zx, t);
    __syncthreads();
    fwd_fft_row(kp, Zk, t);
    __syncthreads();

    #pragma unroll
    for (int s = 0; s < 8; ++s) {
        int j = t + 256*s;
        if (j == 0) {
            float2 zx = Zx[0], zk = Zk[0];
            float ax0 = zx.x + zx.y, axM = zx.x - zx.y;
            float ak0 = zk.x + zk.y, akM = zk.x - zk.y;
            float y0 = ax0*ak0, yM = axM*akM;
            Zx[0] = make_float2(0.5f*(y0+yM), 0.5f*(y0-yM));
            int p2 = swz(8);
            Zx[p2] = cmulf(Zx[p2], Zk[p2]);
        } else {
            int jm = NFFT - j;
            int pj = binpos(j), pm = binpos(jm);
            float2 zxj = Zx[pj], zxm = Zx[pm];
            float2 zkj = Zk[pj], zkm = Zk[pm];
            float sn, cs; __sincosf(-PI_F * (float)j / (float)NFFT, &sn, &cs);
            float2 w = make_float2(cs, sn);
            float2 Xe = make_float2(0.5f*(zxj.x + zxm.x), 0.5f*(zxj.y - zxm.y));
            float2 dx = make_float2(zxj.x - zxm.x, zxj.y + zxm.y);
            float2 Xo = make_float2(0.5f*dx.y, -0.5f*dx.x);
            float2 tx = cmulf(w, Xo);
            float2 Axj = caddf(Xe, tx);
            float2 Axm = make_float2(Xe.x - tx.x, -(Xe.y - tx.y));
            float2 Ke = make_float2(0.5f*(zkj.x + zkm.x), 0.5f*(zkj.y - zkm.y));
            float2 dk = make_float2(zkj.x - zkm.x, zkj.y + zkm.y);
            float2 Ko = make_float2(0.5f*dk.y, -0.5f*dk.x);
            float2 tk = cmulf(w, Ko);
            float2 Akj = caddf(Ke, tk);
            float2 Akm = make_float2(Ke.x - tk.x, -(Ke.y - tk.y));
            float2 Yj = cmulf(Axj, Akj);
            float2 Ym = cmulf(Axm, Akm);
            float2 u  = make_float2(0.5f*(Yj.x + Ym.x), 0.5f*(Yj.y - Ym.y));
            float2 dd = make_float2(Yj.x - Ym.x, Yj.y + Ym.y);
            float2 wc = make_float2(w.x, -w.y);
            float2 vv = cmulf(wc, dd);
            vv.x *= 0.5f; vv.y *= 0.5f;
            Zx[pj] = make_float2(u.x - vv.y, u.y + vv.x);
            Zx[pm] = make_float2(u.x + vv.y, -(u.y - vv.x));
        }
    }
    __syncthreads();

    float2 vx[16], w[16];
    const int k1 = t >> 4, m = t & 15;
    const int rb = 256*k1 + m;
    const int b3 = t << 4;

    #pragma unroll
    for (int r = 0; r < 16; ++r) vx[REV4[r]] = Zx[swz(b3 + r)];
    dit16<1>(vx);
    #pragma unroll
    for (int mm = 0; mm < 16; ++mm) Zx[swz(b3 + mm)] = vx[mm];
    __syncthreads();

    make_tw(TWO_PI_F * (float)m / 256.f, w);
    #pragma unroll
    for (int kk = 0; kk < 16; ++kk) {
        float2 val = Zx[swz(rb + 16*kk)];
        if (kk > 0) val = cmulf(val, w[kk]);
        vx[REV4[kk]] = val;
    }
    dit16<1>(vx);
    #pragma unroll
    for (int r = 0; r < 16; ++r) Zx[swz(rb + 16*r)] = vx[r];
    __syncthreads();

    make_tw(TWO_PI_F * (float)t / (float)NFFT, w);
    #pragma unroll
    for (int kk = 0; kk < 16; ++kk) {
        float2 val = Zx[swz(256*kk + t)];
        if (kk > 0) val = cmulf(val, w[kk]);
        vx[REV4[kk]] = val;
    }
    dit16<1>(vx);
    float2* op = (float2*)(out + ((size_t)(b*H_DIM + hh)) * L_DIM);
    const float sc = 1.f / (float)NFFT;
    #pragma unroll
    for (int n1 = 0; n1 < 8; ++n1) {
        float2 z = vx[n1];
        op[256*n1 + t] = make_float2(z.x*sc, z.y*sc);
    }
}

extern "C" void kernel_launch(void* const* d_in, const int* in_sizes, int n_in,
                              void* d_out, int out_size, void* d_ws, size_t ws_size,
                              hipStream_t stream) {
    const float* x = (const float*)d_in[0];
    const float* k = (const float*)d_in[1];
    float* out = (float*)d_out;
    const size_t need = (size_t)H_DIM * NFFT * sizeof(float2);   // 32 MB
    if (ws_size >= need) {
        float2* Kf = (float2*)d_ws;
        kfft_kernel<<<dim3(H_DIM), dim3(THREADS), 0, stream>>>(k, Kf);
        conv_main_kernel<<<dim3(B_DIM * H_DIM), dim3(THREADS), 0, stream>>>(x, Kf, out);
    } else {
        fftconv_fallback<<<dim3(B_DIM * H_DIM), dim3(THREADS), 0, stream>>>(x, k, out);
    }
}